// Round 11
// baseline (314.145 us; speedup 1.0000x reference)
//
#include <hip/hip_runtime.h>
#include <hip/hip_bf16.h>
#include <stdint.h>

// INSTRUMENTATION ROUND: identical pipeline to R10, but gemm/gather/out loop
// their bodies `reps` times (host passes 8). All three are idempotent, so
// correctness is preserved; per-kernel time = dur/8 and counters become
// visible above the harness fill dispatches. reduce runs once (atomic).
#define NDIM 16384
#define KNB 16
#define BNK_F 1048576.0f

union Pack4 { __hip_bfloat16 h[4]; uint2 u; };

// ---------------- Kernel 1: y1/y2 GEMM (packed-W LDS) ----------------
__global__ __launch_bounds__(256) void gemm_y_kernel(
    const float* __restrict__ x,            // (B, 64, N)
    const float* __restrict__ W,            // (64, 128)
    __hip_bfloat16* __restrict__ y1,        // (B, N, 64) bf16
    __hip_bfloat16* __restrict__ y2,        // (B, N, 64) bf16
    float* __restrict__ stats,              // zeroed here
    int reps)
{
    __shared__ alignas(16) unsigned int lds_w[64 * 68]; // (w1+w2 | w2<<16) bf16
    __shared__ alignas(16) float        lds_x[64 * 68];

    const int tid = threadIdx.x;
    if (blockIdx.x == 0 && tid < 128) stats[tid] = 0.0f;

    const int b  = blockIdx.x >> 8;
    const int n0 = (blockIdx.x & 255) << 6;

    for (int rep = 0; rep < reps; ++rep) {
        for (int i = tid; i < 4096; i += 256) {
            int c = i & 63, o = i >> 6;
            float w1 = W[o * 128 + c];
            float w2 = W[o * 128 + 64 + c];
            unsigned int u12 = (unsigned int)__bfloat16_as_ushort(__float2bfloat16(w1 + w2));
            unsigned int u2  = (unsigned int)__bfloat16_as_ushort(__float2bfloat16(w2));
            lds_w[c * 68 + o] = u12 | (u2 << 16);
        }
        const float* xb = x + (size_t)b * 64 * NDIM + n0;
        for (int i = tid; i < 4096; i += 256) {
            int nl = i & 63, c = i >> 6;
            lds_x[c * 68 + nl] = xb[(size_t)c * NDIM + nl];
        }
        __syncthreads();

        const int o0  = (tid & 15) * 4;
        const int nl0 = (tid >> 4) * 4;
        float acc1[4][4] = {}, acc2[4][4] = {};
        #pragma unroll 4
        for (int c = 0; c < 64; ++c) {
            float4 xv = *(const float4*)&lds_x[c * 68 + nl0];
            uint4  wv = *(const uint4*)&lds_w[c * 68 + o0];
            const float xa[4] = { xv.x, xv.y, xv.z, xv.w };
            const unsigned int wu[4] = { wv.x, wv.y, wv.z, wv.w };
            #pragma unroll
            for (int j = 0; j < 4; ++j) {
                float w12 = __uint_as_float(wu[j] << 16);
                float w2f = __uint_as_float(wu[j] & 0xffff0000u);
                #pragma unroll
                for (int i = 0; i < 4; ++i) {
                    acc1[i][j] = fmaf(w12, xa[i], acc1[i][j]);
                    acc2[i][j] = fmaf(w2f, xa[i], acc2[i][j]);
                }
            }
        }
        const size_t bn0 = (size_t)b * NDIM + n0;
        #pragma unroll
        for (int i = 0; i < 4; ++i) {
            Pack4 p1, p2;
            #pragma unroll
            for (int j = 0; j < 4; ++j) {
                p1.h[j] = __float2bfloat16(acc1[i][j]);
                p2.h[j] = __float2bfloat16(acc2[i][j]);
            }
            size_t off = (bn0 + nl0 + i) * 64 + o0;
            *(uint2*)(y1 + off) = p1.u;
            *(uint2*)(y2 + off) = p2.u;
        }
        __syncthreads();   // protect LDS re-staging next rep
    }
}

// ---------------- Kernel 2: packed gather + extremes + stat partials ----------------
__global__ __launch_bounds__(256, 4) void gather_kernel(
    const unsigned* __restrict__ y1p,        // (B,N,32) bf16-pairs
    const unsigned* __restrict__ y2p,        // (B,N,32) bf16-pairs
    const int* __restrict__ ei,              // (B, N, 16)
    const float* __restrict__ gamma,         // (64)
    unsigned* __restrict__ hselp,            // (B,N,32) bf16-pairs
    float* __restrict__ partials,            // (2048, 128)
    int reps)
{
    const int tid  = threadIdx.x;
    const int w    = __builtin_amdgcn_readfirstlane(tid >> 6);
    const int lane = tid & 63;
    const int half = lane >> 5;
    const int c2   = lane & 31;
    const int g    = blockIdx.x;             // 0..2047
    const int xcd  = g & 7;
    const int b    = xcd >> 1;
    const int hlf  = xcd & 1;
    const int lb   = g >> 3;
    const int row0 = b * NDIM + hlf * 8192 + lb * 32 + w * 8;

    const unsigned sgn0 = (gamma[2 * c2]     >= 0.0f) ? 0x80000000u : 0u;
    const unsigned sgn1 = (gamma[2 * c2 + 1] >= 0.0f) ? 0x80000000u : 0u;
    const unsigned* y2b = y2p + ((size_t)b * NDIM) * 32 + c2;

    __shared__ float rs[8][64];
    __shared__ float rq[8][64];

    for (int rep = 0; rep < reps; ++rep) {
        float ssum0 = 0.f, ssum1 = 0.f, ssq0 = 0.f, ssq1 = 0.f;

        for (int rp = 0; rp < 8; rp += 2) {
            const int ra = row0 + rp;
            const int* iA = ei + (size_t)ra * KNB;
            const int* iB = ei + (size_t)(ra + 1) * KNB;

            unsigned u[KNB];
            #pragma unroll
            for (int k = 0; k < KNB; ++k) {
                int j = half ? iB[k] : iA[k];
                u[k] = y2b[(size_t)j * 32];
            }
            const unsigned y1u = y1p[(size_t)(ra + half) * 32 + c2];

            float s20 = 0.f, s21 = 0.f, q20 = 0.f, q21 = 0.f;
            float M0 = -3.402823e38f, M1 = -3.402823e38f;
            #pragma unroll
            for (int k = 0; k < KNB; ++k) {
                unsigned lo = u[k] << 16;
                unsigned hi = u[k] & 0xffff0000u;
                float v0 = __uint_as_float(lo);
                float v1 = __uint_as_float(hi);
                s20 += v0;               s21 += v1;
                q20 = fmaf(v0, v0, q20); q21 = fmaf(v1, v1, q21);
                M0 = fmaxf(M0, __uint_as_float(lo ^ sgn0));
                M1 = fmaxf(M1, __uint_as_float(hi ^ sgn1));
            }
            const float y1lo = __uint_as_float(y1u << 16);
            const float y1hi = __uint_as_float(y1u & 0xffff0000u);
            const float e0 = __uint_as_float(__float_as_uint(M0) ^ sgn0);
            const float e1 = __uint_as_float(__float_as_uint(M1) ^ sgn1);
            const float h0 = y1lo - e0;
            const float h1 = y1hi - e1;
            unsigned pk = (unsigned)__bfloat16_as_ushort(__float2bfloat16(h0))
                        | ((unsigned)__bfloat16_as_ushort(__float2bfloat16(h1)) << 16);
            hselp[(size_t)(ra + half) * 32 + c2] = pk;
            ssum0 += 16.f * y1lo - s20;
            ssum1 += 16.f * y1hi - s21;
            ssq0  += fmaf(fmaf(-2.f, s20, 16.f * y1lo), y1lo, q20);
            ssq1  += fmaf(fmaf(-2.f, s21, 16.f * y1hi), y1hi, q21);
        }

        __syncthreads();               // protect rs/rq reuse across reps
        rs[w * 2 + half][c2 * 2]     = ssum0;
        rs[w * 2 + half][c2 * 2 + 1] = ssum1;
        rq[w * 2 + half][c2 * 2]     = ssq0;
        rq[w * 2 + half][c2 * 2 + 1] = ssq1;
        __syncthreads();
        if (tid < 128) {
            const int c = tid & 63;
            float v = 0.f;
            if (tid < 64) {
                #pragma unroll
                for (int r = 0; r < 8; ++r) v += rs[r][c];
            } else {
                #pragma unroll
                for (int r = 0; r < 8; ++r) v += rq[r][c];
            }
            partials[(size_t)g * 128 + tid] = v;
        }
    }
}

// ---------------- Kernel 3: parallel reduce partials -> stats ----------------
__global__ __launch_bounds__(256) void reduce_kernel(
    const float* __restrict__ partials,      // (2048, 128)
    float* __restrict__ stats)
{
    __shared__ float lds[256];
    const int tid = threadIdx.x;
    const int c   = tid & 127;
    const int q   = tid >> 7;
    const int r0  = blockIdx.x * 32 + q * 16;
    float acc = 0.f;
    #pragma unroll
    for (int r = 0; r < 16; ++r)
        acc += partials[(size_t)(r0 + r) * 128 + c];
    lds[tid] = acc;
    __syncthreads();
    if (tid < 128) atomicAdd(&stats[tid], lds[tid] + lds[tid + 128]);
}

// ---------------- Kernel 4: finalize + affine + leaky + transpose ----------------
__global__ __launch_bounds__(256) void out_kernel(
    const unsigned* __restrict__ hselp,      // (B,N,32) bf16-pairs
    const float* __restrict__ stats,
    const float* __restrict__ gamma,
    const float* __restrict__ beta,
    float* __restrict__ out,                 // (B, 64, N)
    int reps)
{
    __shared__ float tile[64 * 65];
    __shared__ float sc[64], bi[64];
    const int tid = threadIdx.x;
    if (tid < 64) {
        float mean = stats[tid] * (1.0f / BNK_F);
        float var  = stats[64 + tid] * (1.0f / BNK_F) - mean * mean;
        float s    = gamma[tid] * rsqrtf(var + 1e-5f);
        sc[tid] = s;
        bi[tid] = beta[tid] - mean * s;
    }
    __syncthreads();

    const int b  = blockIdx.x >> 8;
    const int n0 = (blockIdx.x & 255) << 6;
    const size_t bn0 = (size_t)b * NDIM + n0;
    const int c2 = tid & 31;
    const int r0 = tid >> 5;
    const int lane = tid & 63;

    for (int rep = 0; rep < reps; ++rep) {
        for (int r = r0; r < 64; r += 8) {
            unsigned u = hselp[(bn0 + r) * 32 + c2];
            float v0 = fmaf(sc[2 * c2],     __uint_as_float(u << 16),          bi[2 * c2]);
            float v1 = fmaf(sc[2 * c2 + 1], __uint_as_float(u & 0xffff0000u), bi[2 * c2 + 1]);
            v0 = (v0 >= 0.f) ? v0 : 0.2f * v0;
            v1 = (v1 >= 0.f) ? v1 : 0.2f * v1;
            tile[r * 65 + 2 * c2]     = v0;
            tile[r * 65 + 2 * c2 + 1] = v1;
        }
        __syncthreads();
        for (int o = tid >> 6; o < 64; o += 4)
            out[((size_t)(b * 64 + o) << 14) + n0 + lane] = tile[lane * 65 + o];
        __syncthreads();               // protect tile rewrite next rep
    }
}

extern "C" void kernel_launch(void* const* d_in, const int* in_sizes, int n_in,
                              void* d_out, int out_size, void* d_ws, size_t ws_size,
                              hipStream_t stream) {
    const float* x     = (const float*)d_in[0];
    const int*   ei    = (const int*)d_in[1];
    const float* W     = (const float*)d_in[2];
    const float* gamma = (const float*)d_in[3];
    const float* beta  = (const float*)d_in[4];
    float* out = (float*)d_out;

    char* ws = (char*)d_ws;
    __hip_bfloat16* y1    = (__hip_bfloat16*)(ws);                // 8 MiB
    __hip_bfloat16* y2    = (__hip_bfloat16*)(ws + 8388608);      // 8 MiB
    unsigned*       hselp = (unsigned*)(ws + 16777216);           // 8 MiB (bf16 pairs)
    float*          part  = (float*)(ws + 25165824);              // 1 MiB
    float*          stats = (float*)(ws + 25165824 + 1048576);    // 512 B

    const int REPS = 8;   // instrumentation: per-kernel time = dur/8

    gemm_y_kernel <<<dim3(1024), dim3(256), 0, stream>>>(x, W, y1, y2, stats, REPS);
    gather_kernel <<<dim3(2048), dim3(256), 0, stream>>>((const unsigned*)y1, (const unsigned*)y2,
                                                         ei, gamma, hselp, part, REPS);
    reduce_kernel <<<dim3(64),   dim3(256), 0, stream>>>(part, stats);
    out_kernel    <<<dim3(1024), dim3(256), 0, stream>>>(hselp, stats, gamma, beta, out, REPS);
}

// Round 12
// 117.033 us; speedup vs baseline: 2.6842x; 2.6842x over previous
//
#include <hip/hip_runtime.h>
#include <hip/hip_bf16.h>
#include <hip/hip_cooperative_groups.h>
#include <stdint.h>

namespace cg = cooperative_groups;

// B=4, C=64, N=16384, K=16, CO=64 (fp32 I/O, int32 idx)
// R11 finding: kernels sum ~32us, but 4 dispatch gaps cost ~83us (~20us each).
// => single cooperative kernel (1024 blocks = 4/CU, LDS 26.1KB for safe coop
// occupancy; R4 failed at 36.9KB). Fallback to proven R10 pipeline if the
// occupancy guard or coop launch fails (deterministic either way).
#define NDIM 16384
#define KNB 16
#define BNK_F 1048576.0f

union Pack4 { __hip_bfloat16 h[4]; uint2 u; };

__device__ inline unsigned pack_bf16(float a, float b) {
    return (unsigned)__bfloat16_as_ushort(__float2bfloat16(a))
         | ((unsigned)__bfloat16_as_ushort(__float2bfloat16(b)) << 16);
}

// ==================== FUSED cooperative kernel ====================
// Block g owns 64 rows: xcd=g&7 -> b=xcd>>1 (XCD-pinned batch), n0=(xcd&1)*8192+(g>>3)*64.
// Phases: gemm -> sync -> gather+partials -> sync -> reduce(64 blks) -> sync -> out.
__global__ __launch_bounds__(256, 4) void fused_all(
    const float* __restrict__ x,            // (B, 64, N)
    const int* __restrict__ ei,             // (B, N, 16)
    const float* __restrict__ W,            // (64, 128)
    const float* __restrict__ gamma,        // (64)
    const float* __restrict__ beta,         // (64)
    float* __restrict__ out,                // (B, 64, N)
    unsigned* __restrict__ y1p,             // ws (B,N,32) bf16-pairs
    unsigned* __restrict__ y2p,             // ws (B,N,32) bf16-pairs
    unsigned* __restrict__ hselp,           // ws (B,N,32) bf16-pairs
    float* __restrict__ partials,           // ws (1024,128)
    float* __restrict__ stats)              // ws (128)
{
    __shared__ alignas(16) unsigned char smem[26112]; // 17408 (W) + 8704 (x-pairs)
    __shared__ float sc[64], bi[64];
    unsigned* lds_w  = (unsigned*)smem;               // [64*68] (w1+w2 | w2<<16)
    unsigned* lds_xp = (unsigned*)(smem + 17408);     // [64*34] x bf16-pairs
    float*    lds_f  = (float*)smem;                  // reused: rs/rq, reduce, out-tile

    cg::grid_group grid = cg::this_grid();
    const int tid  = threadIdx.x;
    const int g    = blockIdx.x;              // 0..1023
    const int xcd  = g & 7;
    const int b    = xcd >> 1;
    const int n0   = (xcd & 1) * 8192 + (g >> 3) * 64;
    const int row0 = b * NDIM + n0;

    if (g == 0 && tid < 128) stats[tid] = 0.0f;

    // ---------------- phase 0: GEMM (block's own 64-col tile) ----------------
    for (int i = tid; i < 4096; i += 256) {
        int c = i & 63, o = i >> 6;
        float w1 = W[o * 128 + c];
        float w2 = W[o * 128 + 64 + c];
        lds_w[c * 68 + o] = pack_bf16(w1 + w2, w2);
    }
    const float* xb = x + (size_t)b * 64 * NDIM + n0;
    for (int i = tid; i < 2048; i += 256) {
        int np = i & 31, c = i >> 5;
        const float2 xv = *(const float2*)(xb + (size_t)c * NDIM + 2 * np);
        lds_xp[c * 34 + np] = pack_bf16(xv.x, xv.y);
    }
    __syncthreads();
    {
        const int o0  = (tid & 15) * 4;
        const int nl0 = (tid >> 4) * 4;
        float acc1[4][4] = {}, acc2[4][4] = {};
        #pragma unroll 4
        for (int c = 0; c < 64; ++c) {
            uint2 xv = *(const uint2*)&lds_xp[c * 34 + (nl0 >> 1)];
            uint4 wv = *(const uint4*)&lds_w[c * 68 + o0];
            const float xa[4] = { __uint_as_float(xv.x << 16), __uint_as_float(xv.x & 0xffff0000u),
                                  __uint_as_float(xv.y << 16), __uint_as_float(xv.y & 0xffff0000u) };
            const unsigned wu[4] = { wv.x, wv.y, wv.z, wv.w };
            #pragma unroll
            for (int j = 0; j < 4; ++j) {
                float w12 = __uint_as_float(wu[j] << 16);
                float w2f = __uint_as_float(wu[j] & 0xffff0000u);
                #pragma unroll
                for (int i = 0; i < 4; ++i) {
                    acc1[i][j] = fmaf(w12, xa[i], acc1[i][j]);
                    acc2[i][j] = fmaf(w2f, xa[i], acc2[i][j]);
                }
            }
        }
        #pragma unroll
        for (int i = 0; i < 4; ++i) {
            uint2 p1 = { pack_bf16(acc1[i][0], acc1[i][1]), pack_bf16(acc1[i][2], acc1[i][3]) };
            uint2 p2 = { pack_bf16(acc2[i][0], acc2[i][1]), pack_bf16(acc2[i][2], acc2[i][3]) };
            size_t off = (size_t)(row0 + nl0 + i) * 32 + (o0 >> 1);
            *(uint2*)&y1p[off] = p1;
            *(uint2*)&y2p[off] = p2;
        }
    }
    grid.sync();

    // ---------------- phase 1: gather + extremes + stat partials ----------------
    const int w    = __builtin_amdgcn_readfirstlane(tid >> 6);
    const int lane = tid & 63;
    const int half = lane >> 5;              // 0: rowA, 1: rowB
    const int c2   = lane & 31;              // channel-pair
    const unsigned sgn0 = (gamma[2 * c2]     >= 0.0f) ? 0x80000000u : 0u;
    const unsigned sgn1 = (gamma[2 * c2 + 1] >= 0.0f) ? 0x80000000u : 0u;
    const unsigned* y2b = y2p + ((size_t)b * NDIM) * 32 + c2;

    float ssum0 = 0.f, ssum1 = 0.f, ssq0 = 0.f, ssq1 = 0.f;
    const int wrow0 = row0 + w * 16;
    for (int rp = 0; rp < 16; rp += 2) {
        const int ra = wrow0 + rp;
        const int* iA = ei + (size_t)ra * KNB;        // wave-uniform -> s_load
        const int* iB = ei + (size_t)(ra + 1) * KNB;

        unsigned u[KNB];
        #pragma unroll
        for (int k = 0; k < KNB; ++k) {
            int j = half ? iB[k] : iA[k];
            u[k] = y2b[(size_t)j * 32];
        }
        const unsigned y1u = y1p[(size_t)(ra + half) * 32 + c2];

        float s20 = 0.f, s21 = 0.f, q20 = 0.f, q21 = 0.f;
        float M0 = -3.402823e38f, M1 = -3.402823e38f;
        #pragma unroll
        for (int k = 0; k < KNB; ++k) {
            unsigned lo = u[k] << 16;
            unsigned hi = u[k] & 0xffff0000u;
            float v0 = __uint_as_float(lo);
            float v1 = __uint_as_float(hi);
            s20 += v0;               s21 += v1;
            q20 = fmaf(v0, v0, q20); q21 = fmaf(v1, v1, q21);
            M0 = fmaxf(M0, __uint_as_float(lo ^ sgn0));
            M1 = fmaxf(M1, __uint_as_float(hi ^ sgn1));
        }
        const float y1lo = __uint_as_float(y1u << 16);
        const float y1hi = __uint_as_float(y1u & 0xffff0000u);
        const float h0 = y1lo - __uint_as_float(__float_as_uint(M0) ^ sgn0);
        const float h1 = y1hi - __uint_as_float(__float_as_uint(M1) ^ sgn1);
        hselp[(size_t)(ra + half) * 32 + c2] = pack_bf16(h0, h1);
        ssum0 += 16.f * y1lo - s20;
        ssum1 += 16.f * y1hi - s21;
        ssq0  += fmaf(fmaf(-2.f, s20, 16.f * y1lo), y1lo, q20);
        ssq1  += fmaf(fmaf(-2.f, s21, 16.f * y1hi), y1hi, q21);
    }
    {   // per-block combine into partials[g][128] (smem free after grid.sync)
        float* rs = lds_f;           // [8][64]
        float* rq = lds_f + 512;     // [8][64]
        rs[(w * 2 + half) * 64 + c2 * 2]     = ssum0;
        rs[(w * 2 + half) * 64 + c2 * 2 + 1] = ssum1;
        rq[(w * 2 + half) * 64 + c2 * 2]     = ssq0;
        rq[(w * 2 + half) * 64 + c2 * 2 + 1] = ssq1;
        __syncthreads();
        if (tid < 128) {
            const int c = tid & 63;
            float v = 0.f;
            const float* src = (tid < 64) ? rs : rq;
            #pragma unroll
            for (int r = 0; r < 8; ++r) v += src[r * 64 + c];
            partials[(size_t)g * 128 + tid] = v;
        }
    }
    grid.sync();

    // ---------------- phase 2: reduce (blocks 0..63) -> stats ----------------
    if (g < 64) {
        const int c = tid & 127;
        const int r0 = g * 16 + (tid >> 7) * 8;
        float acc = 0.f;
        #pragma unroll
        for (int r = 0; r < 8; ++r)
            acc += partials[(size_t)(r0 + r) * 128 + c];
        lds_f[tid] = acc;
        __syncthreads();
        if (tid < 128) atomicAdd(&stats[tid], lds_f[tid] + lds_f[tid + 128]);
    }
    grid.sync();

    // ---------------- phase 3: finalize + affine + leaky + transpose ----------------
    if (tid < 64) {
        float mean = stats[tid] * (1.0f / BNK_F);
        float var  = stats[64 + tid] * (1.0f / BNK_F) - mean * mean;
        float s    = gamma[tid] * rsqrtf(var + 1e-5f);
        sc[tid] = s;
        bi[tid] = beta[tid] - mean * s;
    }
    __syncthreads();
    float* tile = lds_f;                     // 64 x 65 floats (16640 B)
    for (int r = tid >> 5; r < 64; r += 8) {
        unsigned u = hselp[(size_t)(row0 + r) * 32 + c2];
        float v0 = fmaf(sc[2 * c2],     __uint_as_float(u << 16),          bi[2 * c2]);
        float v1 = fmaf(sc[2 * c2 + 1], __uint_as_float(u & 0xffff0000u), bi[2 * c2 + 1]);
        v0 = (v0 >= 0.f) ? v0 : 0.2f * v0;
        v1 = (v1 >= 0.f) ? v1 : 0.2f * v1;
        tile[r * 65 + 2 * c2]     = v0;
        tile[r * 65 + 2 * c2 + 1] = v1;
    }
    __syncthreads();
    for (int o = tid >> 6; o < 64; o += 4)
        out[((size_t)(b * 64 + o) << 14) + n0 + lane] = tile[lane * 65 + o];
}

// ==================== FALLBACK: proven R10 4-kernel pipeline ====================
__global__ __launch_bounds__(256) void gemm_y_kernel(
    const float* __restrict__ x, const float* __restrict__ W,
    __hip_bfloat16* __restrict__ y1, __hip_bfloat16* __restrict__ y2,
    float* __restrict__ stats)
{
    __shared__ alignas(16) unsigned int lds_w[64 * 68];
    __shared__ alignas(16) float        lds_x[64 * 68];
    const int tid = threadIdx.x;
    if (blockIdx.x == 0 && tid < 128) stats[tid] = 0.0f;
    const int b  = blockIdx.x >> 8;
    const int n0 = (blockIdx.x & 255) << 6;
    for (int i = tid; i < 4096; i += 256) {
        int c = i & 63, o = i >> 6;
        float w1 = W[o * 128 + c], w2 = W[o * 128 + 64 + c];
        lds_w[c * 68 + o] = pack_bf16(w1 + w2, w2);
    }
    const float* xb = x + (size_t)b * 64 * NDIM + n0;
    for (int i = tid; i < 4096; i += 256) {
        int nl = i & 63, c = i >> 6;
        lds_x[c * 68 + nl] = xb[(size_t)c * NDIM + nl];
    }
    __syncthreads();
    const int o0  = (tid & 15) * 4;
    const int nl0 = (tid >> 4) * 4;
    float acc1[4][4] = {}, acc2[4][4] = {};
    #pragma unroll 4
    for (int c = 0; c < 64; ++c) {
        float4 xv = *(const float4*)&lds_x[c * 68 + nl0];
        uint4  wv = *(const uint4*)&lds_w[c * 68 + o0];
        const float xa[4] = { xv.x, xv.y, xv.z, xv.w };
        const unsigned wu[4] = { wv.x, wv.y, wv.z, wv.w };
        #pragma unroll
        for (int j = 0; j < 4; ++j) {
            float w12 = __uint_as_float(wu[j] << 16);
            float w2f = __uint_as_float(wu[j] & 0xffff0000u);
            #pragma unroll
            for (int i = 0; i < 4; ++i) {
                acc1[i][j] = fmaf(w12, xa[i], acc1[i][j]);
                acc2[i][j] = fmaf(w2f, xa[i], acc2[i][j]);
            }
        }
    }
    const size_t bn0 = (size_t)b * NDIM + n0;
    #pragma unroll
    for (int i = 0; i < 4; ++i) {
        Pack4 p1, p2;
        #pragma unroll
        for (int j = 0; j < 4; ++j) {
            p1.h[j] = __float2bfloat16(acc1[i][j]);
            p2.h[j] = __float2bfloat16(acc2[i][j]);
        }
        size_t off = (bn0 + nl0 + i) * 64 + o0;
        *(uint2*)(y1 + off) = p1.u;
        *(uint2*)(y2 + off) = p2.u;
    }
}

__global__ __launch_bounds__(256, 4) void gather_kernel(
    const unsigned* __restrict__ y1p, const unsigned* __restrict__ y2p,
    const int* __restrict__ ei, const float* __restrict__ gamma,
    unsigned* __restrict__ hselp, float* __restrict__ partials)
{
    const int tid  = threadIdx.x;
    const int w    = __builtin_amdgcn_readfirstlane(tid >> 6);
    const int lane = tid & 63;
    const int half = lane >> 5;
    const int c2   = lane & 31;
    const int g    = blockIdx.x;
    const int xcd  = g & 7;
    const int b    = xcd >> 1;
    const int row0 = b * NDIM + (xcd & 1) * 8192 + (g >> 3) * 32 + w * 8;
    const unsigned sgn0 = (gamma[2 * c2]     >= 0.0f) ? 0x80000000u : 0u;
    const unsigned sgn1 = (gamma[2 * c2 + 1] >= 0.0f) ? 0x80000000u : 0u;
    const unsigned* y2b = y2p + ((size_t)b * NDIM) * 32 + c2;
    float ssum0 = 0.f, ssum1 = 0.f, ssq0 = 0.f, ssq1 = 0.f;
    for (int rp = 0; rp < 8; rp += 2) {
        const int ra = row0 + rp;
        const int* iA = ei + (size_t)ra * KNB;
        const int* iB = ei + (size_t)(ra + 1) * KNB;
        unsigned u[KNB];
        #pragma unroll
        for (int k = 0; k < KNB; ++k) {
            int j = half ? iB[k] : iA[k];
            u[k] = y2b[(size_t)j * 32];
        }
        const unsigned y1u = y1p[(size_t)(ra + half) * 32 + c2];
        float s20 = 0.f, s21 = 0.f, q20 = 0.f, q21 = 0.f;
        float M0 = -3.402823e38f, M1 = -3.402823e38f;
        #pragma unroll
        for (int k = 0; k < KNB; ++k) {
            unsigned lo = u[k] << 16, hi = u[k] & 0xffff0000u;
            float v0 = __uint_as_float(lo), v1 = __uint_as_float(hi);
            s20 += v0;               s21 += v1;
            q20 = fmaf(v0, v0, q20); q21 = fmaf(v1, v1, q21);
            M0 = fmaxf(M0, __uint_as_float(lo ^ sgn0));
            M1 = fmaxf(M1, __uint_as_float(hi ^ sgn1));
        }
        const float y1lo = __uint_as_float(y1u << 16);
        const float y1hi = __uint_as_float(y1u & 0xffff0000u);
        const float h0 = y1lo - __uint_as_float(__float_as_uint(M0) ^ sgn0);
        const float h1 = y1hi - __uint_as_float(__float_as_uint(M1) ^ sgn1);
        hselp[(size_t)(ra + half) * 32 + c2] = pack_bf16(h0, h1);
        ssum0 += 16.f * y1lo - s20;
        ssum1 += 16.f * y1hi - s21;
        ssq0  += fmaf(fmaf(-2.f, s20, 16.f * y1lo), y1lo, q20);
        ssq1  += fmaf(fmaf(-2.f, s21, 16.f * y1hi), y1hi, q21);
    }
    __shared__ float rs[8][64];
    __shared__ float rq[8][64];
    rs[w * 2 + half][c2 * 2]     = ssum0;
    rs[w * 2 + half][c2 * 2 + 1] = ssum1;
    rq[w * 2 + half][c2 * 2]     = ssq0;
    rq[w * 2 + half][c2 * 2 + 1] = ssq1;
    __syncthreads();
    if (tid < 128) {
        const int c = tid & 63;
        float v = 0.f;
        if (tid < 64) { for (int r = 0; r < 8; ++r) v += rs[r][c]; }
        else          { for (int r = 0; r < 8; ++r) v += rq[r][c]; }
        partials[(size_t)g * 128 + tid] = v;
    }
}

__global__ __launch_bounds__(256) void reduce_kernel(
    const float* __restrict__ partials, float* __restrict__ stats)
{
    __shared__ float lds[256];
    const int tid = threadIdx.x;
    const int c   = tid & 127;
    const int r0  = blockIdx.x * 32 + (tid >> 7) * 16;
    float acc = 0.f;
    #pragma unroll
    for (int r = 0; r < 16; ++r)
        acc += partials[(size_t)(r0 + r) * 128 + c];
    lds[tid] = acc;
    __syncthreads();
    if (tid < 128) atomicAdd(&stats[tid], lds[tid] + lds[tid + 128]);
}

__global__ __launch_bounds__(256) void out_kernel(
    const unsigned* __restrict__ hselp, const float* __restrict__ stats,
    const float* __restrict__ gamma, const float* __restrict__ beta,
    float* __restrict__ out)
{
    __shared__ float tile[64 * 65];
    __shared__ float sc[64], bi[64];
    const int tid = threadIdx.x;
    if (tid < 64) {
        float mean = stats[tid] * (1.0f / BNK_F);
        float var  = stats[64 + tid] * (1.0f / BNK_F) - mean * mean;
        float s    = gamma[tid] * rsqrtf(var + 1e-5f);
        sc[tid] = s;
        bi[tid] = beta[tid] - mean * s;
    }
    __syncthreads();
    const int b  = blockIdx.x >> 8;
    const int n0 = (blockIdx.x & 255) << 6;
    const size_t bn0 = (size_t)b * NDIM + n0;
    const int c2 = tid & 31;
    for (int r = tid >> 5; r < 64; r += 8) {
        unsigned u = hselp[(bn0 + r) * 32 + c2];
        float v0 = fmaf(sc[2 * c2],     __uint_as_float(u << 16),          bi[2 * c2]);
        float v1 = fmaf(sc[2 * c2 + 1], __uint_as_float(u & 0xffff0000u), bi[2 * c2 + 1]);
        v0 = (v0 >= 0.f) ? v0 : 0.2f * v0;
        v1 = (v1 >= 0.f) ? v1 : 0.2f * v1;
        tile[r * 65 + 2 * c2]     = v0;
        tile[r * 65 + 2 * c2 + 1] = v1;
    }
    __syncthreads();
    const int lane = tid & 63;
    for (int o = tid >> 6; o < 64; o += 4)
        out[((size_t)(b * 64 + o) << 14) + n0 + lane] = tile[lane * 65 + o];
}

extern "C" void kernel_launch(void* const* d_in, const int* in_sizes, int n_in,
                              void* d_out, int out_size, void* d_ws, size_t ws_size,
                              hipStream_t stream) {
    const float* x     = (const float*)d_in[0];
    const int*   ei    = (const int*)d_in[1];
    const float* W     = (const float*)d_in[2];
    const float* gamma = (const float*)d_in[3];
    const float* beta  = (const float*)d_in[4];
    float* out = (float*)d_out;

    char* ws = (char*)d_ws;
    unsigned* y1p   = (unsigned*)(ws);                      // 8 MiB (bf16 pairs)
    unsigned* y2p   = (unsigned*)(ws + 8388608);            // 8 MiB
    unsigned* hselp = (unsigned*)(ws + 16777216);           // 8 MiB
    float*    part  = (float*)(ws + 25165824);              // 1 MiB (covers 2048x128)
    float*    stats = (float*)(ws + 25165824 + 1048576);    // 512 B

    // Deterministic guard: coop launch needs 4 blocks/CU residency.
    int occ = 0;
    hipError_t qerr = hipOccupancyMaxActiveBlocksPerMultiprocessor(
        &occ, (const void*)fused_all, 256, 0);
    if (qerr == hipSuccess && occ >= 4) {
        void* kargs[] = { (void*)&x, (void*)&ei, (void*)&W, (void*)&gamma, (void*)&beta,
                          (void*)&out, (void*)&y1p, (void*)&y2p, (void*)&hselp,
                          (void*)&part, (void*)&stats };
        hipError_t lerr = hipLaunchCooperativeKernel((const void*)fused_all,
                                                     dim3(1024), dim3(256), kargs, 0, stream);
        if (lerr == hipSuccess) return;
    }

    // Fallback: proven R10 pipeline (115 us)
    gemm_y_kernel <<<dim3(1024), dim3(256), 0, stream>>>(x, W, (__hip_bfloat16*)y1p,
                                                         (__hip_bfloat16*)y2p, stats);
    gather_kernel <<<dim3(2048), dim3(256), 0, stream>>>(y1p, y2p, ei, gamma, hselp, part);
    reduce_kernel <<<dim3(64),   dim3(256), 0, stream>>>(part, stats);
    out_kernel    <<<dim3(1024), dim3(256), 0, stream>>>(hselp, stats, gamma, beta, out);
}